// Round 18
// baseline (54.511 us; speedup 1.0000x reference)
//
#include <hip/hip_runtime.h>
#include <math.h>

#define SRf 48000.0f
#define CSOUND 343.0f
#define RIR_LEN 24000
#define TAPS 81
#define HALFT 40
#define NB 8
#define NM 21                 // per-axis entries with order <= 10
#define NTRIP (NM * NM * NM)  // 9261 candidate triples
#define NSL 16                // image-slices per batch
#define NH 2                  // time-halves per slice
#define HLEN (RIR_LEN / NH)   // 12000
#define BLOCK 1024
#define SPT 12                // samples per thread (1000 active threads)
#define CAPS 256              // per-(slice,half) keeper capacity (worst ~120)

// 0.9^q for q = 0..10
__device__ __constant__ float c_beta[11] = {
    1.0f, 0.9f, 0.81f, 0.729f, 0.6561f, 0.59049f, 0.531441f,
    0.4782969f, 0.43046721f, 0.387420489f, 0.3486784401f};

// Per-axis image table restricted to order <= 10 (pure arithmetic):
//   m in [0,10]:  p=0, n=m-5  -> sign=+1, off=2n, order=2|n|
//   m in [11,20]: p=1, n=m-15 -> sign=-1, off=2n, order=|n-1|+|n|
__device__ __forceinline__ void axis_entry(int m, float& sgn, float& off, int& ord) {
    if (m < 11) {
        int n = m - 5;
        sgn = 1.0f;
        off = 2.0f * (float)n;
        ord = 2 * abs(n);
    } else {
        int n = m - 15;
        sgn = -1.0f;
        off = 2.0f * (float)n;
        ord = abs(n - 1) + abs(n);
    }
}

// f32 -> bf16 (round to nearest even)
__device__ __forceinline__ unsigned bfr(float f) {
    unsigned u = __float_as_uint(f);
    return (u + 0x7FFFu + ((u >> 16) & 1u)) >> 16;
}

// kernel 1: block = (batch, slice, half); b = blockIdx%8 -> XCD-local ws.
// GATHER form: each thread owns SPT=12 consecutive samples in REGISTERS;
// loops over the block's images (LDS broadcast) with a wave-uniform skip.
// No LDS tile, no zeroing, no LDS atomics, no staged writeout.
__global__ __launch_bounds__(BLOCK) void k_paint(const float* __restrict__ x,
                                                 unsigned short* __restrict__ ws) {
    __shared__ float4 s_e[CAPS];   // {amp, frac, amp*sin(pi*frac)/pi, i0}
    __shared__ float2 s_f[CAPS];   // {cos(pi*frac/41), sin(pi*frac/41)}
    __shared__ float2 s_win[TAPS]; // {cos(pi*(ki-40)/41), sin(pi*(ki-40)/41)}
    __shared__ int s_cnt;

    const float PIF = 3.14159265358979323846f;
    const int b = blockIdx.x & 7;           // XCD-aligned batch
    const int rest = blockIdx.x >> 3;       // 0..31
    const int sl = rest >> 1;               // 0..15
    const int h = rest & 1;
    const int H0 = h * HLEN;
    const int tid = threadIdx.x;

    const float* xb = x + b * 9;
    const float r0 = xb[0] * 10.0f, r1 = xb[1] * 10.0f, r2 = xb[2] * 10.0f;
    const float m0 = xb[3] * r0, m1 = xb[4] * r1, m2 = xb[5] * r2;
    const float s0 = xb[6] * r0, s1 = xb[7] * r1, s2 = xb[8] * r2;

    if (tid == 0) s_cnt = 0;
    if (tid < TAPS - 1) {  // window-angle table for ki = 1..80
        int ki = tid + 1;
        float A = PIF * (1.0f / 41.0f) * (float)(ki - HALFT);
        s_win[ki] = make_float2(__cosf(A), __sinf(A));
    }
    __syncthreads();

    // ---- phase A: register-only scan of residue class (one candidate/thread)
    {
        int r = sl + tid * NSL;
        if (r < NTRIP) {
            int mi = r / (NM * NM);
            int rem = r - mi * (NM * NM);
            int mj = rem / NM;
            int mk = rem - mj * NM;

            float si, oi_; int qi; axis_entry(mi, si, oi_, qi);
            float sj, oj_; int qj; axis_entry(mj, sj, oj_, qj);
            float sk, ok_; int qk; axis_entry(mk, sk, ok_, qk);
            int q = qi + qj + qk;
            if (q <= 10) {
                float dx = si * s0 + oi_ * r0 - m0;
                float dy = sj * s1 + oj_ * r1 - m1;
                float dz = sk * s2 + ok_ * r2 - m2;
                float dist = sqrtf(dx * dx + dy * dy + dz * dz);

                float tau = SRf * dist / CSOUND;
                float i0f = floorf(tau);
                int i0 = (int)i0f;
                // in-range taps: idx in [i0+41, i0+120]; intersect [H0, H0+HLEN)?
                if (i0 + HALFT + TAPS - 1 >= H0 && i0 + HALFT + 1 < H0 + HLEN) {
                    float fr = tau - i0f;
                    float amp = c_beta[q] / (4.0f * PIF * dist);
                    int slot = atomicAdd(&s_cnt, 1);
                    float4 e;
                    e.x = amp;
                    e.y = fr;
                    e.z = amp * __sinf(PIF * fr) * (1.0f / PIF);
                    e.w = __int_as_float(i0);
                    s_e[slot] = e;
                    float B = PIF * (1.0f / 41.0f) * fr;
                    s_f[slot] = make_float2(__cosf(B), __sinf(B));
                }
            }
        }
    }
    __syncthreads();

    // ---- phase B: GATHER. Thread owns samples [t0, t0+SPT) of this half.
    const int n = s_cnt;
    const int t0 = tid * SPT;
    if (t0 < HLEN) {
        float acc[SPT];
        #pragma unroll
        for (int u = 0; u < SPT; ++u) acc[u] = 0.0f;

        const int wbase = (tid & ~63) * SPT;       // wave's first sample (uniform)
        for (int i = 0; i < n; ++i) {
            float4 e = s_e[i];                     // LDS broadcast read
            int i0 = __float_as_int(e.w);
            int rlo = i0 + HALFT + 1 - H0;         // first valid sample (rel)
            int rhi = i0 + HALFT + TAPS - 1 - H0;  // last valid sample (rel)
            if (rhi < wbase || rlo >= wbase + 64 * SPT) continue;  // wave-uniform

            float2 f2 = s_f[i];
            int base_ki = t0 + H0 - i0 - HALFT;    // ki for u = 0
            #pragma unroll
            for (int u = 0; u < SPT; ++u) {
                int ki = base_ki + u;
                if (ki >= 1 && ki <= TAPS - 1) {
                    float2 wn = s_win[ki];
                    float win = 0.5f + 0.5f * (wn.x * f2.x + wn.y * f2.y);
                    float tt = (float)(ki - HALFT) - e.y;  // in (-40, 40]
                    float v = ((ki & 1) ? e.z : -e.z) * __builtin_amdgcn_rcpf(tt);
                    v = (tt == 0.0f) ? e.x : v;            // exact-integer delay
                    acc[u] += v * win;
                }
            }
        }

        // ---- phase C: bf16 register writeout (3 x 8B stores, 8B-aligned)
        unsigned short* wb = ws + (size_t)((b * NSL + sl) * NH + h) * HLEN + t0;
        uint2 p0, p1, p2;
        p0.x = bfr(acc[0]) | (bfr(acc[1]) << 16);
        p0.y = bfr(acc[2]) | (bfr(acc[3]) << 16);
        p1.x = bfr(acc[4]) | (bfr(acc[5]) << 16);
        p1.y = bfr(acc[6]) | (bfr(acc[7]) << 16);
        p2.x = bfr(acc[8]) | (bfr(acc[9]) << 16);
        p2.y = bfr(acc[10]) | (bfr(acc[11]) << 16);
        *(uint2*)(wb + 0) = p0;
        *(uint2*)(wb + 4) = p1;
        *(uint2*)(wb + 8) = p2;
    }
}

// kernel 2: b = blockIdx%8 (same XCD as producers -> L2-local bf16 reads).
// 192 blocks = 8 batches x 24 segments of 1000 samples.
__global__ __launch_bounds__(256) void k_reduce(const float* __restrict__ x,
                                                const unsigned short* __restrict__ ws,
                                                float* __restrict__ out) {
    const int b = blockIdx.x & 7;
    const int seg = blockIdx.x >> 3;  // 0..23
    const int tid = threadIdx.x;
    int j = seg * 1000 + tid * 4;
    if (tid < 250) {
        int h = j / HLEN;
        int jh = j - h * HLEN;
        const unsigned short* base = ws + (size_t)(b * NSL * NH + h) * HLEN + jh;
        float4 acc = make_float4(0.f, 0.f, 0.f, 0.f);
        #pragma unroll
        for (int s = 0; s < NSL; ++s) {
            ushort4 v = *(const ushort4*)(base + (size_t)s * NH * HLEN);
            acc.x += __uint_as_float((unsigned)v.x << 16);
            acc.y += __uint_as_float((unsigned)v.y << 16);
            acc.z += __uint_as_float((unsigned)v.z << 16);
            acc.w += __uint_as_float((unsigned)v.w << 16);
        }
        *(float4*)(out + (size_t)b * RIR_LEN + j) = acc;
    }
    if (blockIdx.x == 0 && tid < NB) {
        const float* xb = x + tid * 9;
        float r0 = xb[0] * 10.0f, r1 = xb[1] * 10.0f, r2 = xb[2] * 10.0f;
        float d0 = (xb[3] - xb[6]) * r0;
        float d1 = (xb[4] - xb[7]) * r1;
        float d2 = (xb[5] - xb[8]) * r2;
        float dist = sqrtf(d0 * d0 + d1 * d1 + d2 * d2);
        out[NB * RIR_LEN + tid] = 40.0f + SRf * dist / CSOUND;
    }
}

extern "C" void kernel_launch(void* const* d_in, const int* in_sizes, int n_in,
                              void* d_out, int out_size, void* d_ws, size_t ws_size,
                              hipStream_t stream) {
    const float* x = (const float*)d_in[0];
    float* out = (float*)d_out;
    unsigned short* ws = (unsigned short*)d_ws;  // 256*12000 bf16 = 6.14 MB

    k_paint<<<NB * NSL * NH, BLOCK, 0, stream>>>(x, ws);
    k_reduce<<<NB * 24, 256, 0, stream>>>(x, ws, out);
}

// Round 19
// 21.862 us; speedup vs baseline: 2.4935x; 2.4935x over previous
//
#include <hip/hip_runtime.h>
#include <math.h>

#define SRf 48000.0f
#define CSOUND 343.0f
#define RIR_LEN 24000
#define TAPS 81
#define HALFT 40
#define NB 8
#define NM 21                 // per-axis entries with order <= 10
#define NTRIP (NM * NM * NM)  // 9261 candidate triples
#define NSL 16                // image-slices per batch
#define NH 2                  // time-halves per slice
#define HLEN (RIR_LEN / NH)   // 12000
#define BLOCK 1024
#define CAPS 256              // per-(slice,half) keeper capacity (worst ~120)

// 0.9^q for q = 0..10
__device__ __constant__ float c_beta[11] = {
    1.0f, 0.9f, 0.81f, 0.729f, 0.6561f, 0.59049f, 0.531441f,
    0.4782969f, 0.43046721f, 0.387420489f, 0.3486784401f};

// Per-axis image table restricted to order <= 10 (pure arithmetic):
//   m in [0,10]:  p=0, n=m-5  -> sign=+1, off=2n, order=2|n|
//   m in [11,20]: p=1, n=m-15 -> sign=-1, off=2n, order=|n-1|+|n|
__device__ __forceinline__ void axis_entry(int m, float& sgn, float& off, int& ord) {
    if (m < 11) {
        int n = m - 5;
        sgn = 1.0f;
        off = 2.0f * (float)n;
        ord = 2 * abs(n);
    } else {
        int n = m - 15;
        sgn = -1.0f;
        off = 2.0f * (float)n;
        ord = abs(n - 1) + abs(n);
    }
}

// f32 -> bf16 (round to nearest even)
__device__ __forceinline__ unsigned bfr(float f) {
    unsigned u = __float_as_uint(f);
    return (u + 0x7FFFu + ((u >> 16) & 1u)) >> 16;
}

// kernel 1: block = (batch, slice, half) with b = blockIdx%8 so every block of
// batch b lands on XCD b (round-robin dispatch) -> its ws partials stay in that
// XCD's L2 for the reduce. Paint windowed-sinc taps into a 48 KB LDS half-RIR,
// write out as bf16 (values <=~0.5, output threshold 10.12 -> huge headroom).
__global__ __launch_bounds__(BLOCK) void k_paint(const float* __restrict__ x,
                                                 unsigned short* __restrict__ ws) {
    __shared__ __align__(16) float s_tile[HLEN];  // 48 KB private half-RIR
    __shared__ float4 s_e[CAPS];   // {amp, frac, amp*sin(pi*frac)/pi, i0}
    __shared__ float2 s_f[CAPS];   // {cos(pi*frac/41), sin(pi*frac/41)}
    __shared__ float2 s_win[TAPS]; // {cos(pi*(ki-40)/41), sin(pi*(ki-40)/41)}
    __shared__ int s_cnt;

    const float PIF = 3.14159265358979323846f;
    const int b = blockIdx.x & 7;           // XCD-aligned batch
    const int rest = blockIdx.x >> 3;       // 0..31
    const int sl = rest >> 1;
    const int h = rest & 1;
    const int H0 = h * HLEN;
    const int tid = threadIdx.x;

    const float* xb = x + b * 9;
    const float r0 = xb[0] * 10.0f, r1 = xb[1] * 10.0f, r2 = xb[2] * 10.0f;
    const float m0 = xb[3] * r0, m1 = xb[4] * r1, m2 = xb[5] * r2;
    const float s0 = xb[6] * r0, s1 = xb[7] * r1, s2 = xb[8] * r2;

    if (tid == 0) s_cnt = 0;
    if (tid < TAPS - 1) {  // window-angle table for ki = 1..80
        int ki = tid + 1;
        float A = PIF * (1.0f / 41.0f) * (float)(ki - HALFT);
        s_win[ki] = make_float2(__cosf(A), __sinf(A));
    }
    for (int j = tid * 4; j < HLEN; j += BLOCK * 4)
        *(float4*)&s_tile[j] = make_float4(0.f, 0.f, 0.f, 0.f);
    __syncthreads();

    // ---- phase A: register-only scan of residue class (one candidate/thread)
    {
        int r = sl + tid * NSL;
        if (r < NTRIP) {
            int mi = r / (NM * NM);
            int rem = r - mi * (NM * NM);
            int mj = rem / NM;
            int mk = rem - mj * NM;

            float si, oi_; int qi; axis_entry(mi, si, oi_, qi);
            float sj, oj_; int qj; axis_entry(mj, sj, oj_, qj);
            float sk, ok_; int qk; axis_entry(mk, sk, ok_, qk);
            int q = qi + qj + qk;
            if (q <= 10) {
                float dx = si * s0 + oi_ * r0 - m0;
                float dy = sj * s1 + oj_ * r1 - m1;
                float dz = sk * s2 + ok_ * r2 - m2;
                float dist = sqrtf(dx * dx + dy * dy + dz * dz);

                float tau = SRf * dist / CSOUND;
                float i0f = floorf(tau);
                int i0 = (int)i0f;
                // in-range taps: idx in [i0+41, i0+120]; intersect [H0, H0+HLEN)?
                if (i0 + HALFT + TAPS - 1 >= H0 && i0 + HALFT + 1 < H0 + HLEN) {
                    float fr = tau - i0f;
                    float amp = c_beta[q] / (4.0f * PIF * dist);
                    int slot = atomicAdd(&s_cnt, 1);
                    float4 e;
                    e.x = amp;
                    e.y = fr;
                    e.z = amp * __sinf(PIF * fr) * (1.0f / PIF);
                    e.w = __int_as_float(i0);
                    s_e[slot] = e;
                    float B = PIF * (1.0f / 41.0f) * fr;
                    s_f[slot] = make_float2(__cosf(B), __sinf(B));
                }
            }
        }
    }
    __syncthreads();

    // ---- phase B: flattened (image, tap) paint. Tap ki=0 contributes 0.
    // win = 0.5*(1+cos(A-B)) = 0.5*(1 + cA*cB + sA*sB): table + 2 fma, no cosf.
    const int n = s_cnt;
    const int total = n * (TAPS - 1);
    for (int w = tid; w < total; w += BLOCK) {
        int img = w / (TAPS - 1);
        int ki = w - img * (TAPS - 1) + 1;  // 1..80
        float4 e = s_e[img];
        int idx = __float_as_int(e.w) + HALFT + ki - H0;
        if (idx < 0 || idx >= HLEN) continue;

        float2 f2 = s_f[img];
        float2 wn = s_win[ki];
        float win = 0.5f * (1.0f + wn.x * f2.x + wn.y * f2.y);
        float tt = (float)(ki - HALFT) - e.y;  // in (-40, 40]
        float v = ((ki & 1) ? e.z : -e.z) * __builtin_amdgcn_rcpf(tt);
        v = (tt == 0.0f) ? e.x : v;  // exact-integer delay
        atomicAdd(&s_tile[idx], v * win);
    }
    __syncthreads();

    // ---- phase C: bf16 writeout (8 values / 16B store per thread-iter)
    unsigned short* wb = ws + (size_t)((b * NSL + sl) * NH + h) * HLEN;
    for (int j = tid * 8; j < HLEN; j += BLOCK * 8) {
        float4 a = *(const float4*)&s_tile[j];
        float4 c = *(const float4*)&s_tile[j + 4];
        uint4 p;
        p.x = bfr(a.x) | (bfr(a.y) << 16);
        p.y = bfr(a.z) | (bfr(a.w) << 16);
        p.z = bfr(c.x) | (bfr(c.y) << 16);
        p.w = bfr(c.z) | (bfr(c.w) << 16);
        *(uint4*)&wb[j] = p;
    }
}

// kernel 2: b = blockIdx%8 (same XCD as the producers -> L2-local reads).
// 192 blocks = 8 batches x 24 segments of 1000 samples.
__global__ __launch_bounds__(256) void k_reduce(const float* __restrict__ x,
                                                const unsigned short* __restrict__ ws,
                                                float* __restrict__ out) {
    const int b = blockIdx.x & 7;
    const int seg = blockIdx.x >> 3;  // 0..23
    const int tid = threadIdx.x;
    int j = seg * 1000 + tid * 4;
    if (tid < 250) {
        int h = j / HLEN;
        int jh = j - h * HLEN;
        const unsigned short* base = ws + (size_t)(b * NSL * NH + h) * HLEN + jh;
        float4 acc = make_float4(0.f, 0.f, 0.f, 0.f);
        #pragma unroll
        for (int s = 0; s < NSL; ++s) {
            ushort4 v = *(const ushort4*)(base + (size_t)s * NH * HLEN);
            acc.x += __uint_as_float((unsigned)v.x << 16);
            acc.y += __uint_as_float((unsigned)v.y << 16);
            acc.z += __uint_as_float((unsigned)v.z << 16);
            acc.w += __uint_as_float((unsigned)v.w << 16);
        }
        *(float4*)(out + (size_t)b * RIR_LEN + j) = acc;
    }
    if (blockIdx.x == 0 && tid < NB) {
        const float* xb = x + tid * 9;
        float r0 = xb[0] * 10.0f, r1 = xb[1] * 10.0f, r2 = xb[2] * 10.0f;
        float d0 = (xb[3] - xb[6]) * r0;
        float d1 = (xb[4] - xb[7]) * r1;
        float d2 = (xb[5] - xb[8]) * r2;
        float dist = sqrtf(d0 * d0 + d1 * d1 + d2 * d2);
        out[NB * RIR_LEN + tid] = 40.0f + SRf * dist / CSOUND;
    }
}

extern "C" void kernel_launch(void* const* d_in, const int* in_sizes, int n_in,
                              void* d_out, int out_size, void* d_ws, size_t ws_size,
                              hipStream_t stream) {
    const float* x = (const float*)d_in[0];
    float* out = (float*)d_out;
    unsigned short* ws = (unsigned short*)d_ws;  // 256*12000 bf16 = 6.14 MB

    k_paint<<<NB * NSL * NH, BLOCK, 0, stream>>>(x, ws);
    k_reduce<<<NB * 24, 256, 0, stream>>>(x, ws, out);
}